// Round 1
// baseline (396.221 us; speedup 1.0000x reference)
//
#include <hip/hip_runtime.h>
#include <stdint.h>

typedef __attribute__((ext_vector_type(8))) short short8;   // 8 bf16
typedef __attribute__((ext_vector_type(4))) float f32x4;

#define Q_SIZE   16
#define QLEN     32
#define DIM      128
#define D_COUNT  2048
#define DLEN     180
#define NTILES   12      // ceil(180/16): N padded to 192
#define LDS_ROWS 192     // 180 + 12 zero pad rows

// f32 -> bf16 round-to-nearest-even (bit-exact with HW cast)
static __device__ __forceinline__ unsigned short f2bf(float x) {
    union { float f; unsigned int u; } v; v.f = x;
    unsigned int r = v.u + 0x7fffu + ((v.u >> 16) & 1u);
    return (unsigned short)(r >> 16);
}

__global__ __launch_bounds__(512) void maxsim_kernel(
    const float* __restrict__ Q, const float* __restrict__ D,
    float* __restrict__ out)
{
    // D tile in bf16, row stride 256 B, XOR-swizzled: byte ^= (s&7)<<4
    __shared__ __align__(16) unsigned char smem[LDS_ROWS * 256];  // 48 KiB

    const int tid = threadIdx.x;
    const int k   = blockIdx.x;

    // ---- stage D[k] (180x128 f32) -> LDS bf16, swizzled ----
    const float4* Dk = (const float4*)(D + (size_t)k * (DLEN * DIM));
    for (int f = tid; f < DLEN * (DIM / 4); f += 512) {   // 5760 float4s
        float4 v = Dk[f];
        int s = f >> 5;        // 32 float4 per 128-elem row
        int g = f & 31;
        unsigned int off = ((unsigned)(s * 256 + g * 8)) ^ (((unsigned)s & 7u) << 4);
        unsigned long long p =
              (unsigned long long)f2bf(v.x)
            | ((unsigned long long)f2bf(v.y) << 16)
            | ((unsigned long long)f2bf(v.z) << 32)
            | ((unsigned long long)f2bf(v.w) << 48);
        *(unsigned long long*)(smem + off) = p;
    }
    // zero the pad rows 180..191 (avoid poison/NaN in MFMA inputs)
    if (tid < (LDS_ROWS - DLEN) * 32) {   // 384 chunks of 8 B
        int s = DLEN + (tid >> 5);
        int g = tid & 31;
        unsigned int off = ((unsigned)(s * 256 + g * 8)) ^ (((unsigned)s & 7u) << 4);
        *(unsigned long long*)(smem + off) = 0ull;
    }
    __syncthreads();

    const int wave = tid >> 6;
    const int lane = tid & 63;
    const int lr   = lane & 15;   // row-within-tile for A, s-col for B/C
    const int lg   = lane >> 4;   // k-group

    #pragma unroll 1
    for (int qi = 0; qi < 2; ++qi) {
        const int q = wave * 2 + qi;

        // A fragments for this query: afr[mt][ks], lane holds
        // Q[q][mt*16 + (lane&15)][ks*32 + (lane>>4)*8 + 0..7]
        short8 afr[2][4];
        #pragma unroll
        for (int mt = 0; mt < 2; ++mt) {
            #pragma unroll
            for (int ks = 0; ks < 4; ++ks) {
                const float* p = Q + (size_t)(q * QLEN + mt * 16 + lr) * DIM
                                   + ks * 32 + lg * 8;
                float4 a = *(const float4*)p;
                float4 b = *(const float4*)(p + 4);
                short8 fr;
                fr[0] = (short)f2bf(a.x); fr[1] = (short)f2bf(a.y);
                fr[2] = (short)f2bf(a.z); fr[3] = (short)f2bf(a.w);
                fr[4] = (short)f2bf(b.x); fr[5] = (short)f2bf(b.y);
                fr[6] = (short)f2bf(b.z); fr[7] = (short)f2bf(b.w);
                afr[mt][ks] = fr;
            }
        }

        f32x4 rm0 = {-INFINITY, -INFINITY, -INFINITY, -INFINITY};
        f32x4 rm1 = rm0;

        #pragma unroll
        for (int nt = 0; nt < NTILES; ++nt) {
            const int srow = nt * 16 + lr;                 // this lane's s column
            const unsigned int rowbase = (unsigned)srow * 256u;
            const unsigned int sx = (((unsigned)srow) & 7u) << 4;
            f32x4 acc0 = {0.f, 0.f, 0.f, 0.f};
            f32x4 acc1 = {0.f, 0.f, 0.f, 0.f};
            #pragma unroll
            for (int ks = 0; ks < 4; ++ks) {
                // B frag: D[srow][ks*32 + lg*8 + 0..7], swizzled 16B read
                unsigned int off = rowbase + (((unsigned)(ks * 64 + lg * 16)) ^ sx);
                short8 b = *(const short8*)(smem + off);
                acc0 = __builtin_amdgcn_mfma_f32_16x16x32_bf16(afr[0][ks], b, acc0, 0, 0, 0);
                acc1 = __builtin_amdgcn_mfma_f32_16x16x32_bf16(afr[1][ks], b, acc1, 0, 0, 0);
            }
            // merge into running max; mask out pad columns s >= 180
            const bool valid = srow < DLEN;
            #pragma unroll
            for (int i = 0; i < 4; ++i) {
                rm0[i] = fmaxf(rm0[i], valid ? acc0[i] : -INFINITY);
                rm1[i] = fmaxf(rm1[i], valid ? acc1[i] : -INFINITY);
            }
        }

        // max over s: columns live in lane&15 -> xor-reduce over bits 0..3
        #pragma unroll
        for (int m = 1; m <= 8; m <<= 1) {
            #pragma unroll
            for (int i = 0; i < 4; ++i) {
                rm0[i] = fmaxf(rm0[i], __shfl_xor(rm0[i], m, 64));
                rm1[i] = fmaxf(rm1[i], __shfl_xor(rm1[i], m, 64));
            }
        }
        // sum over m: this lane holds rows (lane>>4)*4 + i of both m-tiles
        float part = (rm0[0] + rm0[1]) + (rm0[2] + rm0[3])
                   + (rm1[0] + rm1[1]) + (rm1[2] + rm1[3]);
        part += __shfl_xor(part, 16, 64);
        part += __shfl_xor(part, 32, 64);
        if (lane == 0) out[(size_t)q * D_COUNT + k] = part;
    }
}

extern "C" void kernel_launch(void* const* d_in, const int* in_sizes, int n_in,
                              void* d_out, int out_size, void* d_ws, size_t ws_size,
                              hipStream_t stream) {
    const float* Q = (const float*)d_in[0];
    const float* D = (const float*)d_in[1];
    float* out = (float*)d_out;
    maxsim_kernel<<<dim3(D_COUNT), dim3(512), 0, stream>>>(Q, D, out);
}

// Round 2
// 286.678 us; speedup vs baseline: 1.3821x; 1.3821x over previous
//
#include <hip/hip_runtime.h>

typedef __attribute__((ext_vector_type(8))) short short8;   // 8 bf16
typedef __attribute__((ext_vector_type(4))) float f32x4;

#define QLEN     32
#define DIM      128
#define D_COUNT  2048
#define DLEN     180
#define NTILES   12
#define DOCS     4
#define NBLK     (D_COUNT / DOCS)   // 512 blocks

// f32 -> bf16 round-to-nearest-even
static __device__ __forceinline__ unsigned short f2bf(float x) {
    union { float f; unsigned int u; } v; v.f = x;
    unsigned int r = v.u + 0x7fffu + ((v.u >> 16) & 1u);
    return (unsigned short)(r >> 16);
}

static __device__ __forceinline__ unsigned long long pack4(float4 v) {
    return (unsigned long long)f2bf(v.x)
         | ((unsigned long long)f2bf(v.y) << 16)
         | ((unsigned long long)f2bf(v.z) << 32)
         | ((unsigned long long)f2bf(v.w) << 48);
}

__global__ __launch_bounds__(512, 2) void maxsim_kernel(
    const float* __restrict__ Q, const float* __restrict__ D,
    float* __restrict__ out)
{
    // double-buffered D tile, bf16, row stride 256 B, XOR swizzle (row&7)<<4
    __shared__ __align__(16) unsigned char smem[2][DLEN * 256];   // 2 x 45 KiB

    const int tid  = threadIdx.x;
    const int wave = tid >> 6;
    const int lane = tid & 63;
    const int lr   = lane & 15;   // A row within tile / B-C s column
    const int lg   = lane >> 4;   // k-group

    // ---- preload A fragments for this wave's 2 queries (held in regs) ----
    short8 afr[2][2][4];   // [query][mtile][kstep]
    #pragma unroll
    for (int qi = 0; qi < 2; ++qi) {
        const int q = wave * 2 + qi;
        #pragma unroll
        for (int mt = 0; mt < 2; ++mt) {
            #pragma unroll
            for (int ks = 0; ks < 4; ++ks) {
                const float* p = Q + (size_t)(q * QLEN + mt * 16 + lr) * DIM
                                   + ks * 32 + lg * 8;
                float4 a = *(const float4*)p;
                float4 b = *(const float4*)(p + 4);
                short8 fr;
                fr[0] = (short)f2bf(a.x); fr[1] = (short)f2bf(a.y);
                fr[2] = (short)f2bf(a.z); fr[3] = (short)f2bf(a.w);
                fr[4] = (short)f2bf(b.x); fr[5] = (short)f2bf(b.y);
                fr[6] = (short)f2bf(b.z); fr[7] = (short)f2bf(b.w);
                afr[qi][mt][ks] = fr;
            }
        }
    }

    const int k0 = blockIdx.x * DOCS;
    float4 r[12];   // staging regs: 5760 float4 = 11*512 + 128

    auto issue = [&](int doc) {
        const float4* Dk = (const float4*)(D + (size_t)doc * (DLEN * DIM));
        #pragma unroll
        for (int i = 0; i < 11; ++i) r[i] = Dk[i * 512 + tid];
        if (tid < 128) r[11] = Dk[11 * 512 + tid];
    };
    auto cwrite = [&](int buf) {
        unsigned char* s = smem[buf];
        #pragma unroll
        for (int i = 0; i < 11; ++i) {
            int f = i * 512 + tid;
            int row = f >> 5, g = f & 31;
            unsigned off = ((unsigned)(row * 256 + g * 8)) ^ (((unsigned)row & 7u) << 4);
            *(unsigned long long*)(s + off) = pack4(r[i]);
        }
        if (tid < 128) {
            int f = 11 * 512 + tid;
            int row = f >> 5, g = f & 31;
            unsigned off = ((unsigned)(row * 256 + g * 8)) ^ (((unsigned)row & 7u) << 4);
            *(unsigned long long*)(s + off) = pack4(r[11]);
        }
    };

    // ---- prologue: fill buf0 (doc k0), put doc k0+1 loads in flight ----
    issue(k0);
    cwrite(0);              // compiler inserts vmcnt waits for r[]
    issue(k0 + 1);
    asm volatile("s_waitcnt lgkmcnt(0)" ::: "memory");
    __builtin_amdgcn_s_barrier();   // raw barrier: prefetch loads stay in flight
    asm volatile("" ::: "memory");

    #pragma unroll 1
    for (int j = 0; j < DOCS; ++j) {
        const unsigned char* s = smem[j & 1];

        f32x4 rm[2][2];
        #pragma unroll
        for (int a = 0; a < 2; ++a)
            #pragma unroll
            for (int b = 0; b < 2; ++b)
                rm[a][b] = f32x4{-INFINITY, -INFINITY, -INFINITY, -INFINITY};

        #pragma unroll
        for (int nt = 0; nt < NTILES; ++nt) {
            const int srow = nt * 16 + lr;
            const int rrow = (srow < DLEN) ? srow : srow - 16;   // tail reads valid rows
            const unsigned rowbase = (unsigned)rrow * 256u;
            const unsigned sx = (((unsigned)rrow) & 7u) << 4;
            f32x4 acc[2][2];
            #pragma unroll
            for (int a = 0; a < 2; ++a)
                #pragma unroll
                for (int b = 0; b < 2; ++b)
                    acc[a][b] = f32x4{0.f, 0.f, 0.f, 0.f};
            #pragma unroll
            for (int ks = 0; ks < 4; ++ks) {
                // one B fragment feeds 4 MFMAs (2 queries x 2 m-tiles)
                short8 bf = *(const short8*)(s + rowbase
                             + (((unsigned)(ks * 64 + lg * 16)) ^ sx));
                acc[0][0] = __builtin_amdgcn_mfma_f32_16x16x32_bf16(afr[0][0][ks], bf, acc[0][0], 0, 0, 0);
                acc[0][1] = __builtin_amdgcn_mfma_f32_16x16x32_bf16(afr[0][1][ks], bf, acc[0][1], 0, 0, 0);
                acc[1][0] = __builtin_amdgcn_mfma_f32_16x16x32_bf16(afr[1][0][ks], bf, acc[1][0], 0, 0, 0);
                acc[1][1] = __builtin_amdgcn_mfma_f32_16x16x32_bf16(afr[1][1][ks], bf, acc[1][1], 0, 0, 0);
            }
            const bool valid = (nt < 11) || (lr < DLEN - 176);   // lr < 4 on tail tile
            #pragma unroll
            for (int a = 0; a < 2; ++a)
                #pragma unroll
                for (int b = 0; b < 2; ++b)
                    #pragma unroll
                    for (int i = 0; i < 4; ++i)
                        rm[a][b][i] = fmaxf(rm[a][b][i], valid ? acc[a][b][i] : -INFINITY);
        }

        // max over s (cols live in lane&15)
        #pragma unroll
        for (int m = 1; m <= 8; m <<= 1) {
            #pragma unroll
            for (int a = 0; a < 2; ++a)
                #pragma unroll
                for (int b = 0; b < 2; ++b)
                    #pragma unroll
                    for (int i = 0; i < 4; ++i)
                        rm[a][b][i] = fmaxf(rm[a][b][i], __shfl_xor(rm[a][b][i], m, 64));
        }
        // sum over m
        #pragma unroll
        for (int qi = 0; qi < 2; ++qi) {
            float part = (rm[qi][0][0] + rm[qi][0][1]) + (rm[qi][0][2] + rm[qi][0][3])
                       + (rm[qi][1][0] + rm[qi][1][1]) + (rm[qi][1][2] + rm[qi][1][3]);
            part += __shfl_xor(part, 16, 64);
            part += __shfl_xor(part, 32, 64);
            if (lane == 0)
                out[(size_t)(wave * 2 + qi) * D_COUNT + (k0 + j)] = part;
        }

        if (j + 1 < DOCS) {
            cwrite((j + 1) & 1);          // waits vmcnt on r[], writes other buffer
            if (j + 2 < DOCS) issue(k0 + j + 2);   // next prefetch, stays in flight
            asm volatile("s_waitcnt lgkmcnt(0)" ::: "memory");
            __builtin_amdgcn_s_barrier();
            asm volatile("" ::: "memory");
        }
    }
}

extern "C" void kernel_launch(void* const* d_in, const int* in_sizes, int n_in,
                              void* d_out, int out_size, void* d_ws, size_t ws_size,
                              hipStream_t stream) {
    const float* Q = (const float*)d_in[0];
    const float* D = (const float*)d_in[1];
    float* out = (float*)d_out;
    maxsim_kernel<<<dim3(NBLK), dim3(512), 0, stream>>>(Q, D, out);
}